// Round 7
// baseline (105.214 us; speedup 1.0000x reference)
//
#include <hip/hip_runtime.h>
#include <cstddef>

// packed float2 that is only 4-byte aligned (tap pairs at arbitrary x)
struct __attribute__((packed)) f2v { float x, y; };

__device__ __forceinline__ void interp1d(float c, int size, int& lo, int& hi,
                                         float& fr, float& va) {
  va = (c >= -1.0f && c <= (float)size) ? 1.0f : 0.0f;
  float cc  = fmaxf(c, 0.0f);
  float lof = floorf(cc);
  if (lof >= (float)(size - 1)) {
    lo = size - 1; hi = size - 1; fr = 0.0f;
  } else {
    lo = (int)lof; hi = lo + 1; fr = cc - lof;
  }
}

// ---------------------------------------------------------------------------
// Fused multiscale RoI-align, NCHW fp32 direct (no transpose, no workspace).
// Block = (roi, 32-channel group). Thread t<196 = sample: bin = t>>2,
// sub-sample = t&3 (2x2) -> bin reduction is 2 shfl_xor within a nibble.
// Per-thread interp params live in registers; channel loop = 2 row-pair
// loads + 4 fma + 2 shfl per channel. Features are L3-resident (178 MB).
// ---------------------------------------------------------------------------
__global__ __launch_bounds__(256) void roi_fused_kernel(
    const float* __restrict__ f0, const float* __restrict__ f1,
    const float* __restrict__ f2, const float* __restrict__ f3,
    const float* __restrict__ bboxes, float* __restrict__ out, int R) {
  __shared__ float s_out[32 * 49];

  int blk = blockIdx.x;
  int roi = blk >> 3;
  int cg  = blk & 7;                 // channel group: channels [cg*32, cg*32+32)
  int b   = roi / R;

  const float* bb = bboxes + (size_t)roi * 4;
  float x1 = bb[0], y1 = bb[1], x2 = bb[2], y2 = bb[3];
  float area  = (y2 - y1) * (x2 - x1);
  int   level = (area < 147456.0f) + (area < 36864.0f) + (area < 9216.0f);
  int   H     = 32 << level;         // feature is H x H
  float scale = 1.0f / (float)(32 >> level);
  size_t P    = (size_t)H * H;
  const float* fp = (level == 0) ? f0 : (level == 1) ? f1
                  : (level == 2) ? f2 : f3;
  fp += ((size_t)b * 256 + cg * 32) * P;

  float sx1 = x1 * scale, sy1 = y1 * scale;
  float sx2 = x2 * scale, sy2 = y2 * scale;
  float bin_w = fmaxf(sx2 - sx1, 1.0f) / 7.0f;
  float bin_h = fmaxf(sy2 - sy1, 1.0f) / 7.0f;

  int t = threadIdx.x;
  bool active = t < 196;
  int bin = t >> 2;                  // 0..48 (t<196)
  int sub = t & 3;
  int by  = bin / 7, bx = bin - by * 7;
  int si  = sub >> 1, sj = sub & 1;  // 2x2 sub-sample

  float cy = sy1 + ((float)by + 0.25f + 0.5f * (float)si) * bin_h;
  float cx = sx1 + ((float)bx + 0.25f + 0.5f * (float)sj) * bin_w;

  int yl, yh, xl, xh; float fy, fx, vy, vx;
  interp1d(cy, H, yl, yh, fy, vy);
  interp1d(cx, H, xl, xh, fx, vx);

  float vv  = vy * vx;
  float w00 = (1.f - fy) * (1.f - fx) * vv;
  float w01 = (1.f - fy) * fx * vv;
  float w10 = fy * (1.f - fx) * vv;
  float w11 = fy * fx * vv;

  int  xp    = min(xl, H - 2);       // pair-load base column
  bool shift = (xl > xp);            // xl was H-1 (then fx==0, xh==xl)
  int  o00   = yl * H + xp;
  int  o10   = yh * H + xp;
  if (!active) { w00 = w01 = w10 = w11 = 0.f; o00 = o10 = 0; shift = false; }

  const float* base = fp;
#pragma unroll 4
  for (int c = 0; c < 32; ++c, base += P) {
    f2v r0 = *(const f2v*)(base + o00);
    f2v r1 = *(const f2v*)(base + o10);
    float a0 = shift ? r0.y : r0.x;
    float b0 = shift ? r1.y : r1.x;
    float v = w00 * a0 + w01 * r0.y + w10 * b0 + w11 * r1.y;
    v += __shfl_xor(v, 1);
    v += __shfl_xor(v, 2);
    if (active && sub == 0) s_out[c * 49 + bin] = v * 0.25f;
  }
  __syncthreads();

  // flush 32*49 floats (16B-aligned, contiguous) to out[roi][cg*32 .. +32][.]
  float4*       o4 = (float4*)(out + (size_t)roi * (256 * 49) + cg * (32 * 49));
  const float4* s4 = (const float4*)s_out;
  for (int i = t; i < 32 * 49 / 4; i += 256) o4[i] = s4[i];
}

// ---------------------------------------------------------------------------
extern "C" void kernel_launch(void* const* d_in, const int* in_sizes, int n_in,
                              void* d_out, int out_size, void* d_ws, size_t ws_size,
                              hipStream_t stream) {
  const float* f0 = (const float*)d_in[0];
  const float* f1 = (const float*)d_in[1];
  const float* f2 = (const float*)d_in[2];
  const float* f3 = (const float*)d_in[3];
  const float* bb = (const float*)d_in[4];
  float*      out = (float*)d_out;

  int B = in_sizes[0] / (256 * 32 * 32);   // feat0 is (B,256,32,32)
  int N = in_sizes[4] / 4;                 // total rois
  int R = N / B;

  roi_fused_kernel<<<N * 8, 256, 0, stream>>>(f0, f1, f2, f3, bb, out, R);
}

// Round 8
// 88.453 us; speedup vs baseline: 1.1895x; 1.1895x over previous
//
#include <hip/hip_runtime.h>
#include <hip/hip_bf16.h>
#include <cstddef>

// ---------------------------------------------------------------------------
// bf16 helpers: bf16 pair packed in a uint (low ushort = even channel)
// ---------------------------------------------------------------------------
__device__ __forceinline__ float bflo(unsigned u) { return __uint_as_float(u << 16); }
__device__ __forceinline__ float bfhi(unsigned u) { return __uint_as_float(u & 0xffff0000u); }

__device__ __forceinline__ unsigned pk(float lo, float hi) {
  __hip_bfloat162 h = __float22bfloat162_rn(float2{lo, hi});
  return *reinterpret_cast<unsigned*>(&h);
}

__device__ __forceinline__ void acc8(const uint4& q, float w, float* acc) {
  acc[0] = fmaf(w, bflo(q.x), acc[0]);
  acc[1] = fmaf(w, bfhi(q.x), acc[1]);
  acc[2] = fmaf(w, bflo(q.y), acc[2]);
  acc[3] = fmaf(w, bfhi(q.y), acc[3]);
  acc[4] = fmaf(w, bflo(q.z), acc[4]);
  acc[5] = fmaf(w, bfhi(q.z), acc[5]);
  acc[6] = fmaf(w, bflo(q.w), acc[6]);
  acc[7] = fmaf(w, bfhi(q.w), acc[7]);
}

// ---------------------------------------------------------------------------
// Merged transpose, all 4 levels (unchanged from round 5, bench-best):
// (B, 256, P) fp32 -> (B, P, 256) bf16 in ws. Block tile 32 ch x 256 px with
// q-spread; LDS 16.6 KB -> 8 blocks/CU.
// ---------------------------------------------------------------------------
__global__ __launch_bounds__(256) void tr_all_kernel(
    const float* __restrict__ f0, const float* __restrict__ f1,
    const float* __restrict__ f2, const float* __restrict__ f3,
    ushort* __restrict__ ws,
    int c0_, int c1_, int c2_, int B,
    size_t o1, size_t o2, size_t o3) {
  __shared__ unsigned tile[16 * 260];
  int bid = blockIdx.x;
  int lvl, lidx; const float* src; size_t off;
  if (bid < c0_)      { lvl = 0; lidx = bid;       src = f0; off = 0; }
  else if (bid < c1_) { lvl = 1; lidx = bid - c0_; src = f1; off = o1; }
  else if (bid < c2_) { lvl = 2; lidx = bid - c1_; src = f2; off = o2; }
  else                { lvl = 3; lidx = bid - c2_; src = f3; off = o3; }
  int H   = 32 << lvl;
  int P   = H * H;
  int Q   = P >> 2;
  int npx = P >> 8;
  int chg = lidx / (B * npx);
  int rem = lidx - chg * (B * npx);
  int b   = rem / npx;
  int pxc = rem - b * npx;

  const float* in = src + (size_t)b * 256 * P;
  int t  = threadIdx.x;
  int l  = t & 63, wv = t >> 6;
  int q  = l >> 4, sub = l & 15;
  size_t lbase = (size_t)q * Q + (size_t)pxc * 64 + sub * 4;
#pragma unroll
  for (int j = 0; j < 4; ++j) {
    int pair = wv * 4 + j;
    int ch   = chg * 32 + pair * 2;
    float4 a = *(const float4*)(in + (size_t)ch * P + lbase);
    float4 c = *(const float4*)(in + (size_t)(ch + 1) * P + lbase);
    uint4 v;
    v.x = pk(a.x, c.x); v.y = pk(a.y, c.y);
    v.z = pk(a.z, c.z); v.w = pk(a.w, c.w);
    *(uint4*)&tile[pair * 260 + l * 4] = v;
  }
  __syncthreads();

  ushort* outp = ws + off + (size_t)b * P * 256 + chg * 32;
  int cg = t & 3;
  int p0 = t >> 2;
#pragma unroll
  for (int i = 0; i < 4; ++i) {
    int pxi = p0 + 64 * i;
    int qq  = pxi >> 6, s = pxi & 63;
    size_t px = (size_t)qq * Q + (size_t)pxc * 64 + s;
    uint4 g;
    g.x = tile[(cg * 4 + 0) * 260 + pxi];
    g.y = tile[(cg * 4 + 1) * 260 + pxi];
    g.z = tile[(cg * 4 + 2) * 260 + pxi];
    g.w = tile[(cg * 4 + 3) * 260 + pxi];
    *(uint4*)(outp + px * 256 + cg * 8) = g;
  }
}

// ---------------------------------------------------------------------------
__device__ __forceinline__ void interp1d(float c, int size, int& lo, int& hi,
                                         float& fr, float& va) {
  va = (c >= -1.0f && c <= (float)size) ? 1.0f : 0.0f;
  float cc  = fmaxf(c, 0.0f);
  float lof = floorf(cc);
  if (lof >= (float)(size - 1)) {
    lo = size - 1; hi = size - 1; fr = 0.0f;
  } else {
    lo = (int)lof; hi = lo + 1; fr = cc - lof;
  }
}

// ---------------------------------------------------------------------------
// RoI align from bf16 NHWC ws. Block = (roi, 128-ch half): s_out = 25 KB ->
// 6 blocks/CU (75% occupancy, was 37% at 50 KB). Quarter-wave (16 lanes)
// per bin, lane = 8 ch via one 16 B load; 16 bins in flight.
// Block blk and blk+N share a RoI and (N % 8 == 0) the same XCD/L2.
// ---------------------------------------------------------------------------
__global__ __launch_bounds__(256) void roi_nhwc_kernel(
    const ushort* __restrict__ ws, const float* __restrict__ bboxes,
    float* __restrict__ out, int R, int N,
    size_t o1, size_t o2, size_t o3) {
  __shared__ float s_out[128 * 49];              // [c_local][bin]
  __shared__ int   s_il[2][14], s_ih[2][14];
  __shared__ float s_fr[2][14], s_va[2][14];

  int blk  = blockIdx.x;
  int roi  = blk % N;
  int half = blk / N;                // 0 or 1: channels [half*128, half*128+128)
  int b    = roi / R;
  const float* bb = bboxes + (size_t)roi * 4;
  float x1 = bb[0], y1 = bb[1], x2 = bb[2], y2 = bb[3];

  float area  = (y2 - y1) * (x2 - x1);
  int   level = (area < 147456.0f) + (area < 36864.0f) + (area < 9216.0f);
  int   H     = 32 << level;
  float scale = 1.0f / (float)(32 >> level);
  size_t off  = (level == 0) ? 0 : (level == 1) ? o1 : (level == 2) ? o2 : o3;
  const ushort* fp = ws + off + (size_t)b * H * H * 256 + half * 128;

  float sx1 = x1 * scale, sy1 = y1 * scale;
  float sx2 = x2 * scale, sy2 = y2 * scale;
  float bin_w = fmaxf(sx2 - sx1, 1.0f) / 7.0f;
  float bin_h = fmaxf(sy2 - sy1, 1.0f) / 7.0f;

  int t = threadIdx.x;
  if (t < 28) {
    int   axis  = (t >= 14) ? 1 : 0;
    int   g     = t - axis * 14;
    float start = axis ? sx1 : sy1;
    float binsz = axis ? bin_w : bin_h;
    float grid  = (float)(g >> 1) + 0.25f + 0.5f * (float)(g & 1);
    int lo, hi; float fr, va;
    interp1d(start + grid * binsz, H, lo, hi, fr, va);
    s_il[axis][g] = lo; s_ih[axis][g] = hi;
    s_fr[axis][g] = fr; s_va[axis][g] = va;
  }
  __syncthreads();

  int qw = t >> 4;          // quarter-wave slot 0..15
  int ln = t & 15;
  int c8 = ln * 8;          // local channel (within the 128-ch half)

  for (int bin = qw; bin < 49; bin += 16) {
    int oy = bin / 7, ox = bin - oy * 7;
    float acc[8] = {0.f, 0.f, 0.f, 0.f, 0.f, 0.f, 0.f, 0.f};
#pragma unroll
    for (int sy = 0; sy < 2; ++sy) {
#pragma unroll
      for (int sx = 0; sx < 2; ++sx) {
        int gy = oy * 2 + sy, gx = ox * 2 + sx;
        int   yl = s_il[0][gy], yh = s_ih[0][gy];
        int   xl = s_il[1][gx], xh = s_ih[1][gx];
        float fy = s_fr[0][gy], fx = s_fr[1][gx];
        float vv = s_va[0][gy] * s_va[1][gx];
        float w00 = (1.f - fy) * (1.f - fx) * vv;
        float w01 = (1.f - fy) * fx * vv;
        float w10 = fy * (1.f - fx) * vv;
        float w11 = fy * fx * vv;
        uint4 q00 = *(const uint4*)(fp + ((size_t)(yl * H + xl) * 256 + c8));
        uint4 q01 = *(const uint4*)(fp + ((size_t)(yl * H + xh) * 256 + c8));
        uint4 q10 = *(const uint4*)(fp + ((size_t)(yh * H + xl) * 256 + c8));
        uint4 q11 = *(const uint4*)(fp + ((size_t)(yh * H + xh) * 256 + c8));
        acc8(q00, w00, acc);
        acc8(q01, w01, acc);
        acc8(q10, w10, acc);
        acc8(q11, w11, acc);
      }
    }
#pragma unroll
    for (int k = 0; k < 8; ++k) s_out[(c8 + k) * 49 + bin] = acc[k] * 0.25f;
  }
  __syncthreads();

  float4*       o4 = (float4*)(out + (size_t)roi * (256 * 49) + half * (128 * 49));
  const float4* s4 = (const float4*)s_out;
  for (int i = t; i < 128 * 49 / 4; i += 256) o4[i] = s4[i];
}

// ---------------------------------------------------------------------------
// Fallback: direct NCHW fp32 (used only if ws too small)
// ---------------------------------------------------------------------------
__global__ __launch_bounds__(256) void roi_nchw_kernel(
    const float* __restrict__ f0, const float* __restrict__ f1,
    const float* __restrict__ f2, const float* __restrict__ f3,
    const float* __restrict__ bboxes, float* __restrict__ out, int R) {
  __shared__ float s_out[256 * 49];
  __shared__ int   s_il[2][14], s_ih[2][14];
  __shared__ float s_fr[2][14], s_va[2][14];

  int roi = blockIdx.x;
  int b   = roi / R;
  const float* bb = bboxes + (size_t)roi * 4;
  float x1 = bb[0], y1 = bb[1], x2 = bb[2], y2 = bb[3];
  float area  = (y2 - y1) * (x2 - x1);
  int   level = (area < 147456.0f) + (area < 36864.0f) + (area < 9216.0f);
  int   H     = 32 << level;
  float scale = 1.0f / (float)(32 >> level);
  const float* fp = (level == 0) ? f0 : (level == 1) ? f1
                  : (level == 2) ? f2 : f3;
  fp += (size_t)b * 256 * H * H;

  float sx1 = x1 * scale, sy1 = y1 * scale;
  float sx2 = x2 * scale, sy2 = y2 * scale;
  float bin_w = fmaxf(sx2 - sx1, 1.0f) / 7.0f;
  float bin_h = fmaxf(sy2 - sy1, 1.0f) / 7.0f;

  int t = threadIdx.x;
  if (t < 28) {
    int   axis  = (t >= 14) ? 1 : 0;
    int   g     = t - axis * 14;
    float start = axis ? sx1 : sy1;
    float binsz = axis ? bin_w : bin_h;
    float grid  = (float)(g >> 1) + 0.25f + 0.5f * (float)(g & 1);
    int lo, hi; float fr, va;
    interp1d(start + grid * binsz, H, lo, hi, fr, va);
    s_il[axis][g] = lo; s_ih[axis][g] = hi;
    s_fr[axis][g] = fr; s_va[axis][g] = va;
  }
  __syncthreads();

  int wv = t >> 6, ln = t & 63;
  int c4 = ln * 4;
  size_t chs = (size_t)H * H;

  for (int bin = wv; bin < 49; bin += 4) {
    int oy = bin / 7, ox = bin - oy * 7;
    float a0 = 0.f, a1 = 0.f, a2 = 0.f, a3 = 0.f;
#pragma unroll
    for (int sy = 0; sy < 2; ++sy) {
#pragma unroll
      for (int sx = 0; sx < 2; ++sx) {
        int gy = oy * 2 + sy, gx = ox * 2 + sx;
        int   yl = s_il[0][gy], yh = s_ih[0][gy];
        int   xl = s_il[1][gx], xh = s_ih[1][gx];
        float fy = s_fr[0][gy], fx = s_fr[1][gx];
        float vv = s_va[0][gy] * s_va[1][gx];
        float w00 = (1.f - fy) * (1.f - fx) * vv;
        float w01 = (1.f - fy) * fx * vv;
        float w10 = fy * (1.f - fx) * vv;
        float w11 = fy * fx * vv;
        const float* base = fp + (size_t)c4 * chs;
        size_t i00 = (size_t)yl * H + xl, i01 = (size_t)yl * H + xh;
        size_t i10 = (size_t)yh * H + xl, i11 = (size_t)yh * H + xh;
#pragma unroll
        for (int k = 0; k < 4; ++k) {
          float v = w00 * base[i00 + k * chs] + w01 * base[i01 + k * chs] +
                    w10 * base[i10 + k * chs] + w11 * base[i11 + k * chs];
          if (k == 0) a0 += v; else if (k == 1) a1 += v;
          else if (k == 2) a2 += v; else a3 += v;
        }
      }
    }
    s_out[(c4 + 0) * 49 + bin] = a0 * 0.25f;
    s_out[(c4 + 1) * 49 + bin] = a1 * 0.25f;
    s_out[(c4 + 2) * 49 + bin] = a2 * 0.25f;
    s_out[(c4 + 3) * 49 + bin] = a3 * 0.25f;
  }
  __syncthreads();

  float4*       o4 = (float4*)(out + (size_t)roi * (256 * 49));
  const float4* s4 = (const float4*)s_out;
  for (int i = t; i < 256 * 49 / 4; i += 256) o4[i] = s4[i];
}

// ---------------------------------------------------------------------------
extern "C" void kernel_launch(void* const* d_in, const int* in_sizes, int n_in,
                              void* d_out, int out_size, void* d_ws, size_t ws_size,
                              hipStream_t stream) {
  const float* f[4];
  for (int i = 0; i < 4; ++i) f[i] = (const float*)d_in[i];
  const float* bb  = (const float*)d_in[4];
  float*       out = (float*)d_out;

  int B = in_sizes[0] / (256 * 32 * 32);
  int N = in_sizes[4] / 4;
  int R = N / B;

  size_t P[4] = {1024, 4096, 16384, 65536};
  size_t o1 = (size_t)B * 256 * P[0];
  size_t o2 = o1 + (size_t)B * 256 * P[1];
  size_t o3 = o2 + (size_t)B * 256 * P[2];
  size_t tot = o3 + (size_t)B * 256 * P[3];

  if (ws_size >= tot * sizeof(ushort)) {
    ushort* ws = (ushort*)d_ws;
    int n0 = B * 8 * (int)(P[0] >> 8);
    int n1 = B * 8 * (int)(P[1] >> 8);
    int n2 = B * 8 * (int)(P[2] >> 8);
    int n3 = B * 8 * (int)(P[3] >> 8);
    int c0 = n0, c1 = c0 + n1, c2 = c1 + n2, ctot = c2 + n3;
    tr_all_kernel<<<ctot, 256, 0, stream>>>(f[0], f[1], f[2], f[3], ws,
                                            c0, c1, c2, B, o1, o2, o3);
    roi_nhwc_kernel<<<2 * N, 256, 0, stream>>>(ws, bb, out, R, N, o1, o2, o3);
  } else {
    roi_nchw_kernel<<<N, 256, 0, stream>>>(f[0], f[1], f[2], f[3], bb, out, R);
  }
}

// Round 9
// 84.206 us; speedup vs baseline: 1.2495x; 1.0504x over previous
//
#include <hip/hip_runtime.h>
#include <hip/hip_bf16.h>
#include <cstddef>

// ---------------------------------------------------------------------------
// bf16 helpers: bf16 pair packed in a uint (low ushort = even channel)
// ---------------------------------------------------------------------------
__device__ __forceinline__ float bflo(unsigned u) { return __uint_as_float(u << 16); }
__device__ __forceinline__ float bfhi(unsigned u) { return __uint_as_float(u & 0xffff0000u); }

__device__ __forceinline__ unsigned pk(float lo, float hi) {
  __hip_bfloat162 h = __float22bfloat162_rn(float2{lo, hi});
  return *reinterpret_cast<unsigned*>(&h);
}

__device__ __forceinline__ void acc8(const uint4& q, float w, float* acc) {
  acc[0] = fmaf(w, bflo(q.x), acc[0]);
  acc[1] = fmaf(w, bfhi(q.x), acc[1]);
  acc[2] = fmaf(w, bflo(q.y), acc[2]);
  acc[3] = fmaf(w, bfhi(q.y), acc[3]);
  acc[4] = fmaf(w, bflo(q.z), acc[4]);
  acc[5] = fmaf(w, bfhi(q.z), acc[5]);
  acc[6] = fmaf(w, bflo(q.w), acc[6]);
  acc[7] = fmaf(w, bfhi(q.w), acc[7]);
}

// ---------------------------------------------------------------------------
// Merged transpose, all 4 levels: (B, 256, P) fp32 -> (B, P, 256) bf16 in ws.
// Block tile: 32 ch x 256 px CONTIGUOUS. Each wave-load = 1 KB contiguous
// (64 lanes x float4 = one channel's full 256-px chunk).
// chg is the INNERMOST block coord: 8 consecutive blocks produce all 256
// channels of one px-chunk (complete 512 B output lines, co-temporal -> L3
// merge) and sweep px linearly (page/L3 read locality).
// LDS 16.6 KB -> 8 blocks/CU.
// ---------------------------------------------------------------------------
__global__ __launch_bounds__(256) void tr_all_kernel(
    const float* __restrict__ f0, const float* __restrict__ f1,
    const float* __restrict__ f2, const float* __restrict__ f3,
    ushort* __restrict__ ws,
    int c0_, int c1_, int c2_, int B,   // cumulative block counts, batch size
    size_t o1, size_t o2, size_t o3) {  // ws element offsets of lvl 1,2,3
  __shared__ unsigned tile[16 * 260];   // [pair][px'] pair=0..15, px'=0..255
  int bid = blockIdx.x;
  int lvl, lidx; const float* src; size_t off;
  if (bid < c0_)      { lvl = 0; lidx = bid;       src = f0; off = 0; }
  else if (bid < c1_) { lvl = 1; lidx = bid - c0_; src = f1; off = o1; }
  else if (bid < c2_) { lvl = 2; lidx = bid - c1_; src = f2; off = o2; }
  else                { lvl = 3; lidx = bid - c2_; src = f3; off = o3; }
  int H   = 32 << lvl;
  int P   = H * H;
  int npx = P >> 8;                  // 256-px chunks per image
  int chg = lidx & 7;                // channel group 0..7 (innermost)
  int rem = lidx >> 3;
  int b   = rem / npx;
  int pxc = rem - b * npx;           // px chunk (linear sweep)

  const float* in = src + (size_t)b * 256 * P + (size_t)pxc * 256;
  int t = threadIdx.x;
  int l = t & 63, wv = t >> 6;
#pragma unroll
  for (int j = 0; j < 4; ++j) {
    int pair = wv * 4 + j;           // 0..15
    int ch   = chg * 32 + pair * 2;
    float4 a = *(const float4*)(in + (size_t)ch * P + l * 4);
    float4 c = *(const float4*)(in + (size_t)(ch + 1) * P + l * 4);
    uint4 v;
    v.x = pk(a.x, c.x); v.y = pk(a.y, c.y);
    v.z = pk(a.z, c.z); v.w = pk(a.w, c.w);
    *(uint4*)&tile[pair * 260 + l * 4] = v;
  }
  __syncthreads();

  ushort* outp = ws + off + ((size_t)b * P + (size_t)pxc * 256) * 256 + chg * 32;
  int cg = t & 3;                    // uint4 index within 32-ch segment
  int p0 = t >> 2;                   // 0..63
#pragma unroll
  for (int i = 0; i < 4; ++i) {
    int pxi = p0 + 64 * i;           // px' 0..255
    uint4 g;
    g.x = tile[(cg * 4 + 0) * 260 + pxi];
    g.y = tile[(cg * 4 + 1) * 260 + pxi];
    g.z = tile[(cg * 4 + 2) * 260 + pxi];
    g.w = tile[(cg * 4 + 3) * 260 + pxi];
    *(uint4*)(outp + (size_t)pxi * 256 + cg * 8) = g;
  }
}

// ---------------------------------------------------------------------------
__device__ __forceinline__ void interp1d(float c, int size, int& lo, int& hi,
                                         float& fr, float& va) {
  va = (c >= -1.0f && c <= (float)size) ? 1.0f : 0.0f;
  float cc  = fmaxf(c, 0.0f);
  float lof = floorf(cc);
  if (lof >= (float)(size - 1)) {
    lo = size - 1; hi = size - 1; fr = 0.0f;
  } else {
    lo = (int)lof; hi = lo + 1; fr = cc - lof;
  }
}

// ---------------------------------------------------------------------------
// RoI align from bf16 NHWC ws (round-5 winner, unchanged). Half-wave per bin;
// lane = 8 channels via one 16 B load; 8 bins in flight.
// ---------------------------------------------------------------------------
__global__ __launch_bounds__(256) void roi_nhwc_kernel(
    const ushort* __restrict__ ws, const float* __restrict__ bboxes,
    float* __restrict__ out, int R, size_t o1, size_t o2, size_t o3) {
  __shared__ float s_out[256 * 49];              // [c][bin]
  __shared__ int   s_il[2][14], s_ih[2][14];     // [axis 0=y 1=x][g]
  __shared__ float s_fr[2][14], s_va[2][14];

  int roi = blockIdx.x;
  int b   = roi / R;
  const float* bb = bboxes + (size_t)roi * 4;
  float x1 = bb[0], y1 = bb[1], x2 = bb[2], y2 = bb[3];

  float area  = (y2 - y1) * (x2 - x1);
  int   level = (area < 147456.0f) + (area < 36864.0f) + (area < 9216.0f);
  int   H     = 32 << level;
  float scale = 1.0f / (float)(32 >> level);
  size_t off  = (level == 0) ? 0 : (level == 1) ? o1 : (level == 2) ? o2 : o3;
  const ushort* fp = ws + off + (size_t)b * H * H * 256;

  float sx1 = x1 * scale, sy1 = y1 * scale;
  float sx2 = x2 * scale, sy2 = y2 * scale;
  float bin_w = fmaxf(sx2 - sx1, 1.0f) / 7.0f;
  float bin_h = fmaxf(sy2 - sy1, 1.0f) / 7.0f;

  int t = threadIdx.x;
  if (t < 28) {
    int   axis  = (t >= 14) ? 1 : 0;
    int   g     = t - axis * 14;
    float start = axis ? sx1 : sy1;
    float binsz = axis ? bin_w : bin_h;
    float grid  = (float)(g >> 1) + 0.25f + 0.5f * (float)(g & 1);
    int lo, hi; float fr, va;
    interp1d(start + grid * binsz, H, lo, hi, fr, va);
    s_il[axis][g] = lo; s_ih[axis][g] = hi;
    s_fr[axis][g] = fr; s_va[axis][g] = va;
  }
  __syncthreads();

  int hw = t >> 5;          // half-wave 0..7
  int ln = t & 31;
  int c8 = ln * 8;

  for (int bin = hw; bin < 49; bin += 8) {
    int oy = bin / 7, ox = bin - oy * 7;
    float acc[8] = {0.f, 0.f, 0.f, 0.f, 0.f, 0.f, 0.f, 0.f};
#pragma unroll
    for (int sy = 0; sy < 2; ++sy) {
#pragma unroll
      for (int sx = 0; sx < 2; ++sx) {
        int gy = oy * 2 + sy, gx = ox * 2 + sx;
        int   yl = s_il[0][gy], yh = s_ih[0][gy];
        int   xl = s_il[1][gx], xh = s_ih[1][gx];
        float fy = s_fr[0][gy], fx = s_fr[1][gx];
        float vv = s_va[0][gy] * s_va[1][gx];
        float w00 = (1.f - fy) * (1.f - fx) * vv;
        float w01 = (1.f - fy) * fx * vv;
        float w10 = fy * (1.f - fx) * vv;
        float w11 = fy * fx * vv;
        uint4 q00 = *(const uint4*)(fp + ((size_t)(yl * H + xl) * 256 + c8));
        uint4 q01 = *(const uint4*)(fp + ((size_t)(yl * H + xh) * 256 + c8));
        uint4 q10 = *(const uint4*)(fp + ((size_t)(yh * H + xl) * 256 + c8));
        uint4 q11 = *(const uint4*)(fp + ((size_t)(yh * H + xh) * 256 + c8));
        acc8(q00, w00, acc);
        acc8(q01, w01, acc);
        acc8(q10, w10, acc);
        acc8(q11, w11, acc);
      }
    }
#pragma unroll
    for (int k = 0; k < 8; ++k) s_out[(c8 + k) * 49 + bin] = acc[k] * 0.25f;
  }
  __syncthreads();

  float4*       o4 = (float4*)(out + (size_t)roi * (256 * 49));
  const float4* s4 = (const float4*)s_out;
  for (int i = t; i < 256 * 49 / 4; i += 256) o4[i] = s4[i];
}

// ---------------------------------------------------------------------------
// Fallback: direct NCHW fp32 (used only if ws too small)
// ---------------------------------------------------------------------------
__global__ __launch_bounds__(256) void roi_nchw_kernel(
    const float* __restrict__ f0, const float* __restrict__ f1,
    const float* __restrict__ f2, const float* __restrict__ f3,
    const float* __restrict__ bboxes, float* __restrict__ out, int R) {
  __shared__ float s_out[256 * 49];
  __shared__ int   s_il[2][14], s_ih[2][14];
  __shared__ float s_fr[2][14], s_va[2][14];

  int roi = blockIdx.x;
  int b   = roi / R;
  const float* bb = bboxes + (size_t)roi * 4;
  float x1 = bb[0], y1 = bb[1], x2 = bb[2], y2 = bb[3];
  float area  = (y2 - y1) * (x2 - x1);
  int   level = (area < 147456.0f) + (area < 36864.0f) + (area < 9216.0f);
  int   H     = 32 << level;
  float scale = 1.0f / (float)(32 >> level);
  const float* fp = (level == 0) ? f0 : (level == 1) ? f1
                  : (level == 2) ? f2 : f3;
  fp += (size_t)b * 256 * H * H;

  float sx1 = x1 * scale, sy1 = y1 * scale;
  float sx2 = x2 * scale, sy2 = y2 * scale;
  float bin_w = fmaxf(sx2 - sx1, 1.0f) / 7.0f;
  float bin_h = fmaxf(sy2 - sy1, 1.0f) / 7.0f;

  int t = threadIdx.x;
  if (t < 28) {
    int   axis  = (t >= 14) ? 1 : 0;
    int   g     = t - axis * 14;
    float start = axis ? sx1 : sy1;
    float binsz = axis ? bin_w : bin_h;
    float grid  = (float)(g >> 1) + 0.25f + 0.5f * (float)(g & 1);
    int lo, hi; float fr, va;
    interp1d(start + grid * binsz, H, lo, hi, fr, va);
    s_il[axis][g] = lo; s_ih[axis][g] = hi;
    s_fr[axis][g] = fr; s_va[axis][g] = va;
  }
  __syncthreads();

  int wv = t >> 6, ln = t & 63;
  int c4 = ln * 4;
  size_t chs = (size_t)H * H;

  for (int bin = wv; bin < 49; bin += 4) {
    int oy = bin / 7, ox = bin - oy * 7;
    float a0 = 0.f, a1 = 0.f, a2 = 0.f, a3 = 0.f;
#pragma unroll
    for (int sy = 0; sy < 2; ++sy) {
#pragma unroll
      for (int sx = 0; sx < 2; ++sx) {
        int gy = oy * 2 + sy, gx = ox * 2 + sx;
        int   yl = s_il[0][gy], yh = s_ih[0][gy];
        int   xl = s_il[1][gx], xh = s_ih[1][gx];
        float fy = s_fr[0][gy], fx = s_fr[1][gx];
        float vv = s_va[0][gy] * s_va[1][gx];
        float w00 = (1.f - fy) * (1.f - fx) * vv;
        float w01 = (1.f - fy) * fx * vv;
        float w10 = fy * (1.f - fx) * vv;
        float w11 = fy * fx * vv;
        const float* base = fp + (size_t)c4 * chs;
        size_t i00 = (size_t)yl * H + xl, i01 = (size_t)yl * H + xh;
        size_t i10 = (size_t)yh * H + xl, i11 = (size_t)yh * H + xh;
#pragma unroll
        for (int k = 0; k < 4; ++k) {
          float v = w00 * base[i00 + k * chs] + w01 * base[i01 + k * chs] +
                    w10 * base[i10 + k * chs] + w11 * base[i11 + k * chs];
          if (k == 0) a0 += v; else if (k == 1) a1 += v;
          else if (k == 2) a2 += v; else a3 += v;
        }
      }
    }
    s_out[(c4 + 0) * 49 + bin] = a0 * 0.25f;
    s_out[(c4 + 1) * 49 + bin] = a1 * 0.25f;
    s_out[(c4 + 2) * 49 + bin] = a2 * 0.25f;
    s_out[(c4 + 3) * 49 + bin] = a3 * 0.25f;
  }
  __syncthreads();

  float4*       o4 = (float4*)(out + (size_t)roi * (256 * 49));
  const float4* s4 = (const float4*)s_out;
  for (int i = t; i < 256 * 49 / 4; i += 256) o4[i] = s4[i];
}

// ---------------------------------------------------------------------------
extern "C" void kernel_launch(void* const* d_in, const int* in_sizes, int n_in,
                              void* d_out, int out_size, void* d_ws, size_t ws_size,
                              hipStream_t stream) {
  const float* f[4];
  for (int i = 0; i < 4; ++i) f[i] = (const float*)d_in[i];
  const float* bb  = (const float*)d_in[4];
  float*       out = (float*)d_out;

  int B = in_sizes[0] / (256 * 32 * 32);
  int N = in_sizes[4] / 4;
  int R = N / B;

  size_t P[4] = {1024, 4096, 16384, 65536};
  size_t o1 = (size_t)B * 256 * P[0];
  size_t o2 = o1 + (size_t)B * 256 * P[1];
  size_t o3 = o2 + (size_t)B * 256 * P[2];
  size_t tot = o3 + (size_t)B * 256 * P[3];

  if (ws_size >= tot * sizeof(ushort)) {
    ushort* ws = (ushort*)d_ws;
    int n0 = B * 8 * (int)(P[0] >> 8);
    int n1 = B * 8 * (int)(P[1] >> 8);
    int n2 = B * 8 * (int)(P[2] >> 8);
    int n3 = B * 8 * (int)(P[3] >> 8);
    int c0 = n0, c1 = c0 + n1, c2 = c1 + n2, ctot = c2 + n3;
    tr_all_kernel<<<ctot, 256, 0, stream>>>(f[0], f[1], f[2], f[3], ws,
                                            c0, c1, c2, B, o1, o2, o3);
    roi_nhwc_kernel<<<N, 256, 0, stream>>>(ws, bb, out, R, o1, o2, o3);
  } else {
    roi_nchw_kernel<<<N, 256, 0, stream>>>(f[0], f[1], f[2], f[3], bb, out, R);
  }
}